// Round 2
// baseline (233.275 us; speedup 1.0000x reference)
//
#include <hip/hip_runtime.h>
#include <math.h>

#define BB 32
#define QQ 300
#define CC 91
#define TOPK 50
#define NKEEP 256
#define ML 128
#define QC (QQ * CC)        // 27300
#define QC4 (QC / 4)        // 6825 float4s (exact)
#define NPT4 7              // ceil(6825/1024)
#define NWAVE 16
#define CAP 2048            // max boundary-bin candidates for direct ranking

// output layout (flat float32, reference return order)
#define OFF_SCORES ((size_t)0)
#define OFF_LABELS ((size_t)1600)
#define OFF_BOXES  ((size_t)3200)
#define OFF_MASKS  ((size_t)9600)
#define OFF_SI     ((size_t)26224000)
#define OFF_LI     ((size_t)26225600)
#define OFF_LA     ((size_t)26227200)

__device__ __forceinline__ uint32_t fkey(float f) {
    uint32_t u = __float_as_uint(f);
    return (u >> 31) ? ~u : (u | 0x80000000u);
}

// ---------------- fused: table init (block 0) + exact radix top-k, one block/batch ----------------
// Early-exit radix: for N(0,1) logits the pass-0 boundary bin holds ~620 keys,
// so we exit after ONE histogram pass and rank candidates directly in LDS.
__global__ __launch_bounds__(1024) void topk_kernel(const float* __restrict__ logits,
                                                    const float* __restrict__ bbox,
                                                    const float* __restrict__ actions,
                                                    const int* __restrict__ tsz,
                                                    float* __restrict__ out,
                                                    int* __restrict__ wsQ,
                                                    float* __restrict__ wsD,
                                                    int* __restrict__ wsZZ) {
    int b = blockIdx.x;
    int t = threadIdx.x;

    // ---- block 0: build DCT rows 0..22 (fp64, matches numpy) + zigzag table ----
    if (b == 0) {
        for (int idx = t; idx < 23 * 128; idx += 1024) {
            int k = idx >> 7, m = idx & 127;
            double v = cos((M_PI * (2.0 * (double)m + 1.0) * (double)k) / 256.0) * 0.125;
            if (k == 0) v *= sqrt(0.5);
            wsD[idx] = (float)v;
        }
        if (t < NKEEP) {
            int j = t;
            int s = 0;
            while ((s + 1) * (s + 2) / 2 <= j) ++s;
            int o = j - s * (s + 1) / 2;
            int r = (s & 1) ? o : (s - o);
            int c = s - r;
            wsZZ[j] = (r << 5) | c;
        }
    }

    __shared__ uint32_t hist[NWAVE * 256];   // per-wave privatized histograms (16 KB)
    __shared__ uint32_t scn[256];            // summed per-bin counts
    __shared__ uint32_t sP;
    __shared__ int      sNeed, sCnt;
    __shared__ uint32_t cKey[TOPK];
    __shared__ int      cIdx[TOPK];
    __shared__ int      cntGt, cntC;
    __shared__ uint32_t candK[CAP];          // boundary-bin candidates (8 KB)
    __shared__ int      candI[CAP];          // (8 KB)
    __shared__ int      sMin;

    // ---- load keys (float4) ----
    const float4* base4 = (const float4*)(logits + (size_t)b * QC);
    uint32_t key[NPT4][4];
#pragma unroll
    for (int i = 0; i < NPT4; ++i) {
        int p4 = t + 1024 * i;
        if (p4 < QC4) {
            float4 v = base4[p4];
            key[i][0] = fkey(v.x); key[i][1] = fkey(v.y);
            key[i][2] = fkey(v.z); key[i][3] = fkey(v.w);
        } else {
            key[i][0] = key[i][1] = key[i][2] = key[i][3] = 0u;  // below all real keys
        }
    }

    if (t == 0) { cntGt = 0; cntC = 0; }

    int lane = t & 63, w = t >> 6;
    uint32_t* myh = &hist[w * 256];

    // ---- MSB-first radix, exiting as soon as boundary-bin count <= CAP ----
    uint32_t P = 0, topmask = 0;   // keys with (key & topmask) == P are candidates
    int need = TOPK;               // how many to take from the candidate set
    int nCand = QC;
    for (int pass = 0; pass < 4; ++pass) {
        int shift = 24 - 8 * pass;
        for (int i = t; i < NWAVE * 256; i += 1024) hist[i] = 0;
        __syncthreads();
#pragma unroll
        for (int i = 0; i < NPT4; ++i) {
#pragma unroll
            for (int c = 0; c < 4; ++c) {
                uint32_t k = key[i][c];
                if ((k & topmask) == P) atomicAdd(&myh[(k >> shift) & 255u], 1u);
            }
        }
        __syncthreads();
        // sum 16 wave-hists -> scn[bin] (threads 0..255, conflict-free)
        if (t < 256) {
            uint32_t s = 0;
#pragma unroll
            for (int ww = 0; ww < NWAVE; ++ww) s += hist[ww * 256 + t];
            scn[t] = s;
        }
        __syncthreads();
        // wave 0: register suffix-scan over 256 bins, pick boundary bin
        if (t < 64) {
            uint4 h4 = *(const uint4*)&scn[lane * 4];
            uint32_t s3 = h4.w;
            uint32_t s2 = h4.z + s3;
            uint32_t s1 = h4.y + s2;
            uint32_t s0 = h4.x + s1;
            uint32_t inc = s0;
#pragma unroll
            for (int off = 1; off < 64; off <<= 1) {
                uint32_t v = __shfl_down(inc, off);
                if (lane + off < 64) inc += v;
            }
            uint32_t higher = inc - s0;   // strictly-higher lanes' total
            uint32_t sarr[4] = {s0, s1, s2, s3};
            uint32_t harr[4] = {h4.x, h4.y, h4.z, h4.w};
#pragma unroll
            for (int c = 0; c < 4; ++c) {
                int cge = (int)(sarr[c] + higher);
                int cgt = cge - (int)harr[c];
                if (cge >= need && cgt < need) {
                    sP = P | ((uint32_t)(lane * 4 + c) << shift);
                    sNeed = need - cgt;
                    sCnt = (int)harr[c];
                }
            }
        }
        __syncthreads();
        P = sP; need = sNeed; nCand = sCnt;
        topmask = 0xFFFFFFFFu << shift;
        if (nCand <= CAP) break;     // expected: pass 0
    }

    int cgt = TOPK - need;           // count of keys with (key & topmask) > P

    // ---- compaction: definite-top keys + boundary-bin candidates ----
#pragma unroll
    for (int i = 0; i < NPT4; ++i) {
#pragma unroll
        for (int c = 0; c < 4; ++c) {
            uint32_t k = key[i][c];
            uint32_t km = k & topmask;
            if (km > P) {
                int pos = atomicAdd(&cntGt, 1);
                cKey[pos] = k; cIdx[pos] = 4 * (t + 1024 * i) + c;
            } else if (km == P) {
                int pos = atomicAdd(&cntC, 1);
                if (pos < CAP) { candK[pos] = k; candI[pos] = 4 * (t + 1024 * i) + c; }
            }
        }
    }
    __syncthreads();

    int nc = cntC;
    if (nc <= CAP) {
        // direct exact ranking of candidates (key desc, idx asc); broadcast LDS reads
        for (int jj = t; jj < nc; jj += 1024) {
            uint32_t mk = candK[jj]; int mi = candI[jj];
            int rank = 0;
            for (int m = 0; m < nc; ++m) {
                uint32_t ok = candK[m]; int oi = candI[m];
                rank += (ok > mk) || (ok == mk && oi < mi);
            }
            if (rank < need) { cKey[cgt + rank] = mk; cIdx[cgt + rank] = mi; }
        }
        __syncthreads();
    } else {
        // pathological ties (only reachable after pass 3: all candidates == P exactly):
        // take the `need` smallest indices by iterative extraction
        for (int r = 0; r < need; ++r) {
            if (t == 0) sMin = 0x7fffffff;
            __syncthreads();
            int loc = 0x7fffffff;
#pragma unroll
            for (int i = 0; i < NPT4; ++i)
#pragma unroll
                for (int c = 0; c < 4; ++c)
                    if (key[i][c] == P) loc = min(loc, 4 * (t + 1024 * i) + c);
            atomicMin(&sMin, loc);
            __syncthreads();
            int m = sMin;
#pragma unroll
            for (int i = 0; i < NPT4; ++i)
#pragma unroll
                for (int c = 0; c < 4; ++c)
                    if (4 * (t + 1024 * i) + c == m) key[i][c] = 0;
            if (t == 0) { cKey[cgt + r] = P; cIdx[cgt + r] = m; }
            __syncthreads();
        }
    }

    // ---- rank 50 candidates (key desc, index asc) and emit ----
    if (t < TOPK) {
        uint32_t myk = cKey[t]; int myi = cIdx[t];
        int rank = 0;
        for (int m = 0; m < TOPK; ++m) {
            uint32_t ok = cKey[m]; int oi = cIdx[m];
            rank += (ok > myk) || (ok == myk && oi < myi);
        }
        uint32_t u = (myk >> 31) ? (myk & 0x7fffffffu) : ~myk;
        float val = __uint_as_float(u);
        int q = myi / CC;
        int label = myi - q * CC;
        out[OFF_SCORES + b * TOPK + rank] = 1.0f / (1.0f + expf(-val));
        out[OFF_LABELS + b * TOPK + rank] = (float)label;
        wsQ[b * TOPK + rank] = q;
        const float* bbp = bbox + ((size_t)(b * QQ + q)) * 4;
        float cx = bbp[0], cy = bbp[1], bw = bbp[2], bh = bbp[3];
        float ih = (float)tsz[b * 2 + 0];
        float iw = (float)tsz[b * 2 + 1];
        float* bo = out + OFF_BOXES + ((size_t)(b * TOPK + rank)) * 4;
        bo[0] = (cx - 0.5f * bw) * iw;
        bo[1] = (cy - 0.5f * bh) * ih;
        bo[2] = (cx + 0.5f * bw) * iw;
        bo[3] = (cy + 0.5f * bh) * ih;
    }
    if (t == 0) {
        const float* ap = actions + (size_t)b * 10;
        float bv = ap[0]; int bi = 0;
        for (int i = 1; i < 10; ++i) { if (ap[i] > bv) { bv = ap[i]; bi = i; } }
        out[OFF_LA + b] = (float)bi;
    }
}

// ---------------- per-(b,rank) mask DCT + threshold + interms ----------------
// 512 threads, 4x8 register tile per thread (32 acc VGPRs); __launch_bounds__(512, 8)
// forces the <=64-VGPR occupancy band -> 32 waves/CU (2x the 256-thread/8x8 version).
__global__ __launch_bounds__(512, 8) void mask_kernel(const float* __restrict__ vec,
                                                      const float* __restrict__ interms,
                                                      const int* __restrict__ wsQ,
                                                      const float* __restrict__ wsD,
                                                      const int* __restrict__ wsZZ,
                                                      float* __restrict__ out) {
    int j = blockIdx.x;      // rank 0..49
    int b = blockIdx.y;      // batch
    int t = threadIdx.x;

    __shared__ float sD[23 * 128];
    __shared__ float sT[23 * 128];
    __shared__ float sB[23 * 24];
    __shared__ float redv[8];
    __shared__ int   redi[8];
    __shared__ float redmn[8], redmx[8];

    int q = wsQ[b * TOPK + j];

    for (int i = t; i < 23 * 128; i += 512) sD[i] = wsD[i];
    for (int i = t; i < 23 * 24; i += 512) sB[i] = 0.0f;
    __syncthreads();

    // scatter the 256 kept coefficients into zigzag positions (k+l <= 22)
    if (t < NKEEP) {
        int kl = wsZZ[t];
        float x = vec[((size_t)(b * QQ + q)) * NKEEP + t];
        sB[(kl >> 5) * 24 + (kl & 31)] = x;
    }

    // interms argmax/max over 91 classes (sigmoid is monotone)
    int lane = t & 63, w = t >> 6;
    {
        float x = (t < CC) ? interms[((size_t)(b * QQ + q)) * CC + t] : -INFINITY;
        int xi = (t < CC) ? t : 0x7fffffff;
#pragma unroll
        for (int off = 32; off >= 1; off >>= 1) {
            float ov = __shfl_down(x, off);
            int   oi = __shfl_down(xi, off);
            bool better = (ov > x) || (ov == x && oi < xi);
            x = better ? ov : x;
            xi = better ? oi : xi;
        }
        if (lane == 0) { redv[w] = x; redi[w] = xi; }
    }
    __syncthreads();   // guards sB scatter + redv/redi

    if (t == 0) {
        float gv = redv[0]; int gi = redi[0];
        for (int k = 1; k < 8; ++k) {
            bool better = (redv[k] > gv) || (redv[k] == gv && redi[k] < gi);
            gv = better ? redv[k] : gv;
            gi = better ? redi[k] : gi;
        }
        out[OFF_SI + (size_t)b * TOPK + j] = 1.0f / (1.0f + expf(-gv));
        out[OFF_LI + (size_t)b * TOPK + j] = (float)gi;
    }

    // stage 1: T[l][n] = sum_k D[k][n] * B[k][l]   (k,l in 0..22)
    {
        int n = t & 127, h = t >> 7;   // h in 0..3
        float Dn[23];
#pragma unroll
        for (int k = 0; k < 23; ++k) Dn[k] = sD[k * 128 + n];
        for (int l = h; l < 23; l += 4) {
            float acc1 = 0.0f;
#pragma unroll
            for (int k = 0; k < 23; ++k) acc1 += Dn[k] * sB[k * 24 + l];
            sT[l * 128 + n] = acc1;
        }
    }
    __syncthreads();

    // stage 2: out[n][m] = sum_l T[l][n] * D[l][m]  -- 4x8 register tile per thread
    int tr = t >> 4, tc = t & 15;     // tr 0..31 (4 rows each), tc 0..15 (8 cols each)
    float acc[4][8];
#pragma unroll
    for (int a = 0; a < 4; ++a)
#pragma unroll
        for (int c = 0; c < 8; ++c) acc[a][c] = 0.0f;

#pragma unroll
    for (int l = 0; l < 23; ++l) {
        const float4 Tv4 = *(const float4*)&sT[l * 128 + tr * 4];
        const float4 Da = *(const float4*)&sD[l * 128 + tc * 8];
        const float4 Db = *(const float4*)&sD[l * 128 + tc * 8 + 4];
        float Tv[4] = {Tv4.x, Tv4.y, Tv4.z, Tv4.w};
        float Dv[8] = {Da.x, Da.y, Da.z, Da.w, Db.x, Db.y, Db.z, Db.w};
#pragma unroll
        for (int a = 0; a < 4; ++a)
#pragma unroll
            for (int c = 0; c < 8; ++c) acc[a][c] += Tv[a] * Dv[c];
    }

    // block min/max
    float mn = acc[0][0], mx = acc[0][0];
#pragma unroll
    for (int a = 0; a < 4; ++a)
#pragma unroll
        for (int c = 0; c < 8; ++c) {
            mn = fminf(mn, acc[a][c]);
            mx = fmaxf(mx, acc[a][c]);
        }
#pragma unroll
    for (int off = 32; off >= 1; off >>= 1) {
        mn = fminf(mn, __shfl_down(mn, off));
        mx = fmaxf(mx, __shfl_down(mx, off));
    }
    if (lane == 0) { redmn[w] = mn; redmx[w] = mx; }
    __syncthreads();
    float gmn = redmn[0], gmx = redmx[0];
#pragma unroll
    for (int k = 1; k < 8; ++k) {
        gmn = fminf(gmn, redmn[k]);
        gmx = fmaxf(gmx, redmx[k]);
    }
    float thr = 0.5f * (gmx + gmn);

    size_t bse = OFF_MASKS + ((size_t)(b * TOPK + j)) * 16384 + (size_t)tc * 8;
#pragma unroll
    for (int a = 0; a < 4; ++a) {
        int n = tr * 4 + a;
        float4 w0 = make_float4(acc[a][0] > thr ? 1.0f : 0.0f,
                                acc[a][1] > thr ? 1.0f : 0.0f,
                                acc[a][2] > thr ? 1.0f : 0.0f,
                                acc[a][3] > thr ? 1.0f : 0.0f);
        float4 w1 = make_float4(acc[a][4] > thr ? 1.0f : 0.0f,
                                acc[a][5] > thr ? 1.0f : 0.0f,
                                acc[a][6] > thr ? 1.0f : 0.0f,
                                acc[a][7] > thr ? 1.0f : 0.0f);
        *(float4*)&out[bse + (size_t)n * 128]     = w0;
        *(float4*)&out[bse + (size_t)n * 128 + 4] = w1;
    }
}

extern "C" void kernel_launch(void* const* d_in, const int* in_sizes, int n_in,
                              void* d_out, int out_size, void* d_ws, size_t ws_size,
                              hipStream_t stream) {
    const float* logits  = (const float*)d_in[0];
    const float* bbox    = (const float*)d_in[1];
    const float* vec     = (const float*)d_in[2];
    const float* interms = (const float*)d_in[3];
    const float* actions = (const float*)d_in[4];
    const int*   tsz     = (const int*)d_in[5];
    float* out = (float*)d_out;

    float* wsD  = (float*)d_ws;            // 23*128 = 2944 floats
    int*   wsZZ = (int*)(wsD + 2944);      // 256 ints
    int*   wsQ  = wsZZ + 256;              // 1600 ints

    hipLaunchKernelGGL(topk_kernel, dim3(BB), dim3(1024), 0, stream,
                       logits, bbox, actions, tsz, out, wsQ, wsD, wsZZ);
    hipLaunchKernelGGL(mask_kernel, dim3(TOPK, BB), dim3(512), 0, stream,
                       vec, interms, wsQ, wsD, wsZZ, out);
}

// Round 3
// 163.322 us; speedup vs baseline: 1.4283x; 1.4283x over previous
//
#include <hip/hip_runtime.h>
#include <math.h>

#define BB 32
#define QQ 300
#define CC 91
#define TOPK 50
#define NKEEP 256
#define ML 128
#define QC (QQ * CC)        // 27300
#define QC4 (QC / 4)        // 6825 float4s (exact)
#define NPT4 7              // ceil(6825/1024)
#define NWAVE 16
#define NSLICE 8            // histogram slices per batch
#define SL4 854             // ceil(6825/8) float4s per slice
#define CAP 2048            // max boundary-bin candidates for the fast path

// output layout (flat float32, reference return order)
#define OFF_SCORES ((size_t)0)
#define OFF_LABELS ((size_t)1600)
#define OFF_BOXES  ((size_t)3200)
#define OFF_MASKS  ((size_t)9600)
#define OFF_SI     ((size_t)26224000)
#define OFF_LI     ((size_t)26225600)
#define OFF_LA     ((size_t)26227200)

__device__ __forceinline__ uint32_t fkey(float f) {
    uint32_t u = __float_as_uint(f);
    return (u >> 31) ? ~u : (u | 0x80000000u);
}

// wave-0 helper: given 256-bin counts, pick boundary bin for the kth largest.
// Executed by threads 0..63 (one full wave). Writes bin index, #to-take-in-bin, bin count.
__device__ __forceinline__ void pick_boundary(const uint32_t* bins, int kth, int lane,
                                              uint32_t* sBin, int* sNeed, int* sCnt) {
    uint4 h4 = *(const uint4*)&bins[lane * 4];
    uint32_t s3 = h4.w;
    uint32_t s2 = h4.z + s3;
    uint32_t s1 = h4.y + s2;
    uint32_t s0 = h4.x + s1;
    uint32_t inc = s0;
#pragma unroll
    for (int off = 1; off < 64; off <<= 1) {
        uint32_t v = __shfl_down(inc, off);
        if (lane + off < 64) inc += v;
    }
    uint32_t higher = inc - s0;   // strictly-higher lanes' total
    uint32_t sarr[4] = {s0, s1, s2, s3};
    uint32_t harr[4] = {h4.x, h4.y, h4.z, h4.w};
#pragma unroll
    for (int c = 0; c < 4; ++c) {
        int cge = (int)(sarr[c] + higher);
        int cgt = cge - (int)harr[c];
        if (cge >= kth && cgt < kth) {
            *sBin = (uint32_t)(lane * 4 + c);
            *sNeed = kth - cgt;
            *sCnt = (int)harr[c];
        }
    }
}

// ---------------- K1: pass-0 byte histogram, 8 slices/batch = 256 blocks (full chip) ------------
// Each block writes its slice histogram to a DISJOINT global slot (plain stores, no zero/atomics).
// Blocks on the b==0 row also build the DCT + zigzag tables.
__global__ __launch_bounds__(256) void topk_hist(const float* __restrict__ logits,
                                                 float* __restrict__ wsD,
                                                 int* __restrict__ wsZZ,
                                                 uint32_t* __restrict__ wsH) {
    int s = blockIdx.x;   // slice 0..7
    int b = blockIdx.y;   // batch
    int t = threadIdx.x;

    // table init spread over the 8 b==0 blocks (fp64 cos, matches numpy)
    if (b == 0) {
        int lo = s * 368, hi = lo + 368;
        if (hi > 23 * 128) hi = 23 * 128;
        for (int idx = lo + t; idx < hi; idx += 256) {
            int k = idx >> 7, m = idx & 127;
            double v = cos((M_PI * (2.0 * (double)m + 1.0) * (double)k) / 256.0) * 0.125;
            if (k == 0) v *= sqrt(0.5);
            wsD[idx] = (float)v;
        }
        if (s == 0) {
            int j = t;
            int ss = 0;
            while ((ss + 1) * (ss + 2) / 2 <= j) ++ss;
            int o = j - ss * (ss + 1) / 2;
            int r = (ss & 1) ? o : (ss - o);
            int c = ss - r;
            wsZZ[j] = (r << 5) | c;
        }
    }

    __shared__ uint32_t hw[4 * 256];   // per-wave privatized (4 waves)
    for (int i = t; i < 4 * 256; i += 256) hw[i] = 0;
    __syncthreads();

    uint32_t* myh = &hw[(t >> 6) * 256];
    const float4* base4 = (const float4*)(logits + (size_t)b * QC);
    int lo4 = s * SL4;
    int hi4 = lo4 + SL4; if (hi4 > QC4) hi4 = QC4;
    for (int p4 = lo4 + t; p4 < hi4; p4 += 256) {
        float4 v = base4[p4];
        atomicAdd(&myh[fkey(v.x) >> 24], 1u);
        atomicAdd(&myh[fkey(v.y) >> 24], 1u);
        atomicAdd(&myh[fkey(v.z) >> 24], 1u);
        atomicAdd(&myh[fkey(v.w) >> 24], 1u);
    }
    __syncthreads();

    if (t < 256) {
        uint32_t sum = hw[t] + hw[256 + t] + hw[512 + t] + hw[768 + t];
        wsH[((size_t)(b * NSLICE + s)) * 256 + t] = sum;
    }
}

// ---------------- K2: boundary pick + compaction + candidate-only radix refine + emit ----------
__global__ __launch_bounds__(1024) void topk_select(const float* __restrict__ logits,
                                                    const float* __restrict__ bbox,
                                                    const float* __restrict__ actions,
                                                    const int* __restrict__ tsz,
                                                    float* __restrict__ out,
                                                    int* __restrict__ wsQ,
                                                    const uint32_t* __restrict__ wsH) {
    int b = blockIdx.x;
    int t = threadIdx.x;
    int lane = t & 63, w = t >> 6;

    __shared__ uint32_t histw[NWAVE * 256];                       // slow path (16 KB)
    __shared__ __attribute__((aligned(16))) uint32_t h2[256];     // refine hist
    __shared__ __attribute__((aligned(16))) uint32_t scn[256];
    __shared__ uint32_t sP;
    __shared__ int      sNeed, sCnt;
    __shared__ uint32_t cKey[TOPK];
    __shared__ int      cIdx[TOPK];
    __shared__ int      cntTop, cntN, cntE, sMin;
    __shared__ uint32_t candK[2][CAP];                            // 16 KB
    __shared__ int      candI[2][CAP];                            // 16 KB

    // ---- load keys (float4) ----
    const float4* base4 = (const float4*)(logits + (size_t)b * QC);
    uint32_t key[NPT4][4];
#pragma unroll
    for (int i = 0; i < NPT4; ++i) {
        int p4 = t + 1024 * i;
        if (p4 < QC4) {
            float4 v = base4[p4];
            key[i][0] = fkey(v.x); key[i][1] = fkey(v.y);
            key[i][2] = fkey(v.z); key[i][3] = fkey(v.w);
        } else {
            key[i][0] = key[i][1] = key[i][2] = key[i][3] = 0u;  // pads (guarded out below)
        }
    }

    // ---- sum the 8 slice histograms -> scn, pick pass-0 boundary bin ----
    if (t < 256) {
        uint32_t ssum = 0;
#pragma unroll
        for (int s = 0; s < NSLICE; ++s) ssum += wsH[((size_t)(b * NSLICE + s)) * 256 + t];
        scn[t] = ssum;
    }
    if (t == 0) { cntTop = 0; cntN = 0; cntE = 0; }
    __syncthreads();
    if (t < 64) pick_boundary(scn, TOPK, lane, &sP, &sNeed, &sCnt);
    __syncthreads();
    uint32_t P0 = sP << 24;     // boundary byte as full-key prefix
    int need = sNeed;           // how many to take from the boundary bin
    int nC0 = sCnt;             // boundary-bin population

    if (nC0 <= CAP) {
        // ============ FAST PATH ============
        // compact: byte > boundary -> definite top; byte == boundary -> candidate
#pragma unroll
        for (int i = 0; i < NPT4; ++i) {
            int p4 = t + 1024 * i;
#pragma unroll
            for (int c = 0; c < 4; ++c) {
                if (p4 >= QC4) continue;
                uint32_t k = key[i][c];
                uint32_t hb = k & 0xFF000000u;
                if (hb > P0) {
                    int pos = atomicAdd(&cntTop, 1);
                    cKey[pos] = k; cIdx[pos] = 4 * p4 + c;
                } else if (hb == P0) {
                    int pos = atomicAdd(&cntN, 1);
                    candK[0][pos] = k; candI[0][pos] = 4 * p4 + c;
                }
            }
        }
        __syncthreads();
        int nc = cntN;          // == nC0
        int cur = 0;

        // refine with 8-bit radix levels over candidates only
        for (int level = 1; level <= 3; ++level) {
            if (nc <= need) break;       // uniform: nc >= need invariant => nc == need
            int shift = 24 - 8 * level;
            if (t < 256) h2[t] = 0;
            if (t == 0) cntN = 0;
            __syncthreads();
            for (int j2 = t; j2 < nc; j2 += 1024)
                atomicAdd(&h2[(candK[cur][j2] >> shift) & 255u], 1u);
            __syncthreads();
            if (t < 64) pick_boundary(h2, need, lane, &sP, &sNeed, &sCnt);
            __syncthreads();
            uint32_t sub = sP;
            int needN = sNeed;
            for (int j2 = t; j2 < nc; j2 += 1024) {
                uint32_t k2 = candK[cur][j2]; int i2 = candI[cur][j2];
                uint32_t sb = (k2 >> shift) & 255u;
                if (sb > sub) {
                    int pos = atomicAdd(&cntTop, 1);
                    cKey[pos] = k2; cIdx[pos] = i2;
                } else if (sb == sub) {
                    int pos = atomicAdd(&cntN, 1);
                    candK[cur ^ 1][pos] = k2; candI[cur ^ 1][pos] = i2;
                }
            }
            __syncthreads();
            nc = cntN; need = needN; cur ^= 1;
        }

        int base = cntTop;   // uniform (post-barrier, no pending atomics)
        if (nc <= need) {
            // exactly `need` survivors: take all
            for (int j2 = t; j2 < nc; j2 += 1024) {
                cKey[base + j2] = candK[cur][j2];
                cIdx[base + j2] = candI[cur][j2];
            }
        } else {
            // survivors share the exact full key: take `need` smallest indices
            for (int j2 = t; j2 < nc; j2 += 1024) {
                int my = candI[cur][j2];
                int rank = 0;
                for (int m = 0; m < nc; ++m) rank += (candI[cur][m] < my);
                if (rank < need) { cKey[base + rank] = candK[cur][j2]; cIdx[base + rank] = my; }
            }
        }
        __syncthreads();
    } else {
        // ============ SLOW FALLBACK (Round-0 passes 1..3 + proven tie handling) ============
        uint32_t Pfull = P0;
        int kth = need;
        uint32_t* myh = &histw[w * 256];
        for (int pass = 1; pass < 4; ++pass) {
            int shift = 24 - 8 * pass;
            for (int i2 = t; i2 < NWAVE * 256; i2 += 1024) histw[i2] = 0;
            __syncthreads();
            uint32_t pmask = 0xFFFFFFFFu << (shift + 8);
#pragma unroll
            for (int i2 = 0; i2 < NPT4; ++i2)
#pragma unroll
                for (int c = 0; c < 4; ++c) {
                    uint32_t k2 = key[i2][c];
                    if ((k2 & pmask) == Pfull) atomicAdd(&myh[(k2 >> shift) & 255u], 1u);
                }
            __syncthreads();
            if (t < 256) {
                uint32_t ssum = 0;
#pragma unroll
                for (int ww = 0; ww < NWAVE; ++ww) ssum += histw[ww * 256 + t];
                scn[t] = ssum;
            }
            __syncthreads();
            if (t < 64) pick_boundary(scn, kth, lane, &sP, &sNeed, &sCnt);
            __syncthreads();
            Pfull |= (sP << shift);
            kth = sNeed;
        }
        // compaction: > Pfull definite tops; == Pfull ties by smallest index
        if (t == 0) { cntTop = 0; cntE = 0; }
        __syncthreads();
#pragma unroll
        for (int i2 = 0; i2 < NPT4; ++i2) {
            int p4 = t + 1024 * i2;
#pragma unroll
            for (int c = 0; c < 4; ++c) {
                if (p4 >= QC4) continue;
                uint32_t k2 = key[i2][c];
                if (k2 > Pfull) {
                    int pos = atomicAdd(&cntTop, 1);
                    cKey[pos] = k2; cIdx[pos] = 4 * p4 + c;
                } else if (k2 == Pfull) {
                    int pos = atomicAdd(&cntE, 1);
                    if (pos < CAP) candI[0][pos] = 4 * p4 + c;
                }
            }
        }
        __syncthreads();
        int cgt2 = cntTop;   // == TOPK - kth
        int ne = cntE;
        if (ne <= CAP) {
            for (int j2 = t; j2 < ne; j2 += 1024) {
                int my = candI[0][j2];
                int rank = 0;
                for (int m = 0; m < ne; ++m) rank += (candI[0][m] < my);
                if (rank < kth) { cKey[cgt2 + rank] = Pfull; cIdx[cgt2 + rank] = my; }
            }
            __syncthreads();
        } else {
            for (int r = 0; r < kth; ++r) {
                if (t == 0) sMin = 0x7fffffff;
                __syncthreads();
                int loc = 0x7fffffff;
#pragma unroll
                for (int i2 = 0; i2 < NPT4; ++i2) {
                    int p4 = t + 1024 * i2;
#pragma unroll
                    for (int c = 0; c < 4; ++c)
                        if (p4 < QC4 && key[i2][c] == Pfull) loc = min(loc, 4 * p4 + c);
                }
                atomicMin(&sMin, loc);
                __syncthreads();
                int m = sMin;
#pragma unroll
                for (int i2 = 0; i2 < NPT4; ++i2) {
                    int p4 = t + 1024 * i2;
#pragma unroll
                    for (int c = 0; c < 4; ++c)
                        if (4 * p4 + c == m) key[i2][c] = 0;
                }
                if (t == 0) { cKey[cgt2 + r] = Pfull; cIdx[cgt2 + r] = m; }
                __syncthreads();
            }
        }
    }

    // ---- rank 50 winners (key desc, index asc) and emit ----
    if (t < TOPK) {
        uint32_t myk = cKey[t]; int myi = cIdx[t];
        int rank = 0;
        for (int m = 0; m < TOPK; ++m) {
            uint32_t ok = cKey[m]; int oi = cIdx[m];
            rank += (ok > myk) || (ok == myk && oi < myi);
        }
        uint32_t u = (myk >> 31) ? (myk & 0x7fffffffu) : ~myk;
        float val = __uint_as_float(u);
        int q = myi / CC;
        int label = myi - q * CC;
        out[OFF_SCORES + b * TOPK + rank] = 1.0f / (1.0f + expf(-val));
        out[OFF_LABELS + b * TOPK + rank] = (float)label;
        wsQ[b * TOPK + rank] = q;
        const float* bbp = bbox + ((size_t)(b * QQ + q)) * 4;
        float cx = bbp[0], cy = bbp[1], bw = bbp[2], bh = bbp[3];
        float ih = (float)tsz[b * 2 + 0];
        float iw = (float)tsz[b * 2 + 1];
        float* bo = out + OFF_BOXES + ((size_t)(b * TOPK + rank)) * 4;
        bo[0] = (cx - 0.5f * bw) * iw;
        bo[1] = (cy - 0.5f * bh) * ih;
        bo[2] = (cx + 0.5f * bw) * iw;
        bo[3] = (cy + 0.5f * bh) * ih;
    }
    if (t == 0) {
        const float* ap = actions + (size_t)b * 10;
        float bv = ap[0]; int bi = 0;
        for (int i = 1; i < 10; ++i) { if (ap[i] > bv) { bv = ap[i]; bi = i; } }
        out[OFF_LA + b] = (float)bi;
    }
}

// ---------------- per-(b,rank) mask DCT + threshold + interms (Round-0 known-good) -------------
__global__ __launch_bounds__(256) void mask_kernel(const float* __restrict__ vec,
                                                   const float* __restrict__ interms,
                                                   const int* __restrict__ wsQ,
                                                   const float* __restrict__ wsD,
                                                   const int* __restrict__ wsZZ,
                                                   float* __restrict__ out) {
    int j = blockIdx.x;      // rank 0..49
    int b = blockIdx.y;      // batch
    int t = threadIdx.x;

    __shared__ float sD[23 * 128];
    __shared__ float sT[23 * 128];
    __shared__ float sB[23 * 24];
    __shared__ float redv[4];
    __shared__ int   redi[4];
    __shared__ float redmn[4], redmx[4];

    int q = wsQ[b * TOPK + j];

    for (int i = t; i < 23 * 128; i += 256) sD[i] = wsD[i];
    for (int i = t; i < 23 * 24; i += 256) sB[i] = 0.0f;
    __syncthreads();

    // scatter the 256 kept coefficients into zigzag positions (k+l <= 22)
    {
        int kl = wsZZ[t];
        float x = vec[((size_t)(b * QQ + q)) * NKEEP + t];
        sB[(kl >> 5) * 24 + (kl & 31)] = x;
    }

    // interms argmax/max over 91 classes (sigmoid is monotone)
    int lane = t & 63, w = t >> 6;
    {
        float x = (t < CC) ? interms[((size_t)(b * QQ + q)) * CC + t] : -INFINITY;
        int xi = (t < CC) ? t : 0x7fffffff;
#pragma unroll
        for (int off = 32; off >= 1; off >>= 1) {
            float ov = __shfl_down(x, off);
            int   oi = __shfl_down(xi, off);
            bool better = (ov > x) || (ov == x && oi < xi);
            x = better ? ov : x;
            xi = better ? oi : xi;
        }
        if (lane == 0) { redv[w] = x; redi[w] = xi; }
    }
    __syncthreads();   // guards sB scatter + redv/redi

    if (t == 0) {
        float gv = redv[0]; int gi = redi[0];
        for (int k = 1; k < 4; ++k) {
            bool better = (redv[k] > gv) || (redv[k] == gv && redi[k] < gi);
            gv = better ? redv[k] : gv;
            gi = better ? redi[k] : gi;
        }
        out[OFF_SI + (size_t)b * TOPK + j] = 1.0f / (1.0f + expf(-gv));
        out[OFF_LI + (size_t)b * TOPK + j] = (float)gi;
    }

    // stage 1: T[l][n] = sum_k D[k][n] * B[k][l]   (k,l in 0..22)
    {
        int n = t & 127, h = t >> 7;
        float Dn[23];
#pragma unroll
        for (int k = 0; k < 23; ++k) Dn[k] = sD[k * 128 + n];
        for (int l = h; l < 23; l += 2) {
            float acc = 0.0f;
#pragma unroll
            for (int k = 0; k < 23; ++k) acc += Dn[k] * sB[k * 24 + l];
            sT[l * 128 + n] = acc;
        }
    }
    __syncthreads();

    // stage 2: out[n][m] = sum_l T[l][n] * D[l][m]  -- 8x8 register tile per thread
    int tr = t >> 4, tc = t & 15;
    float acc[8][8];
#pragma unroll
    for (int a = 0; a < 8; ++a)
#pragma unroll
        for (int c = 0; c < 8; ++c) acc[a][c] = 0.0f;

#pragma unroll
    for (int l = 0; l < 23; ++l) {
        const float4 Ta = *(const float4*)&sT[l * 128 + tr * 8];
        const float4 Tb = *(const float4*)&sT[l * 128 + tr * 8 + 4];
        const float4 Da = *(const float4*)&sD[l * 128 + tc * 8];
        const float4 Db = *(const float4*)&sD[l * 128 + tc * 8 + 4];
        float Tv[8] = {Ta.x, Ta.y, Ta.z, Ta.w, Tb.x, Tb.y, Tb.z, Tb.w};
        float Dv[8] = {Da.x, Da.y, Da.z, Da.w, Db.x, Db.y, Db.z, Db.w};
#pragma unroll
        for (int a = 0; a < 8; ++a)
#pragma unroll
            for (int c = 0; c < 8; ++c) acc[a][c] += Tv[a] * Dv[c];
    }

    // block min/max
    float mn = acc[0][0], mx = acc[0][0];
#pragma unroll
    for (int a = 0; a < 8; ++a)
#pragma unroll
        for (int c = 0; c < 8; ++c) {
            mn = fminf(mn, acc[a][c]);
            mx = fmaxf(mx, acc[a][c]);
        }
#pragma unroll
    for (int off = 32; off >= 1; off >>= 1) {
        mn = fminf(mn, __shfl_down(mn, off));
        mx = fmaxf(mx, __shfl_down(mx, off));
    }
    if (lane == 0) { redmn[w] = mn; redmx[w] = mx; }
    __syncthreads();
    float gmn = fminf(fminf(redmn[0], redmn[1]), fminf(redmn[2], redmn[3]));
    float gmx = fmaxf(fmaxf(redmx[0], redmx[1]), fmaxf(redmx[2], redmx[3]));
    float thr = 0.5f * (gmx + gmn);

    size_t bse = OFF_MASKS + ((size_t)(b * TOPK + j)) * 16384 + (size_t)tc * 8;
#pragma unroll
    for (int a = 0; a < 8; ++a) {
        int n = tr * 8 + a;
        float4 w0 = make_float4(acc[a][0] > thr ? 1.0f : 0.0f,
                                acc[a][1] > thr ? 1.0f : 0.0f,
                                acc[a][2] > thr ? 1.0f : 0.0f,
                                acc[a][3] > thr ? 1.0f : 0.0f);
        float4 w1 = make_float4(acc[a][4] > thr ? 1.0f : 0.0f,
                                acc[a][5] > thr ? 1.0f : 0.0f,
                                acc[a][6] > thr ? 1.0f : 0.0f,
                                acc[a][7] > thr ? 1.0f : 0.0f);
        *(float4*)&out[bse + (size_t)n * 128]     = w0;
        *(float4*)&out[bse + (size_t)n * 128 + 4] = w1;
    }
}

extern "C" void kernel_launch(void* const* d_in, const int* in_sizes, int n_in,
                              void* d_out, int out_size, void* d_ws, size_t ws_size,
                              hipStream_t stream) {
    const float* logits  = (const float*)d_in[0];
    const float* bbox    = (const float*)d_in[1];
    const float* vec     = (const float*)d_in[2];
    const float* interms = (const float*)d_in[3];
    const float* actions = (const float*)d_in[4];
    const int*   tsz     = (const int*)d_in[5];
    float* out = (float*)d_out;

    float*    wsD  = (float*)d_ws;             // 23*128 = 2944 floats
    int*      wsZZ = (int*)(wsD + 2944);       // 256 ints
    int*      wsQ  = wsZZ + 256;               // 1600 ints
    uint32_t* wsH  = (uint32_t*)(wsQ + 1600);  // 32*8*256 = 65536 u32 (256 KB)

    hipLaunchKernelGGL(topk_hist, dim3(NSLICE, BB), dim3(256), 0, stream,
                       logits, wsD, wsZZ, wsH);
    hipLaunchKernelGGL(topk_select, dim3(BB), dim3(1024), 0, stream,
                       logits, bbox, actions, tsz, out, wsQ, wsH);
    hipLaunchKernelGGL(mask_kernel, dim3(TOPK, BB), dim3(256), 0, stream,
                       vec, interms, wsQ, wsD, wsZZ, out);
}

// Round 4
// 161.560 us; speedup vs baseline: 1.4439x; 1.0109x over previous
//
#include <hip/hip_runtime.h>
#include <math.h>

#define BB 32
#define QQ 300
#define CC 91
#define TOPK 50
#define NKEEP 256
#define ML 128
#define QC (QQ * CC)        // 27300
#define QC4 (QC / 4)        // 6825 float4s (exact)
#define NPT4 7              // ceil(6825/1024)
#define NWAVE 16
#define NSLICE 8            // histogram slices per batch
#define SL4 854             // ceil(6825/8) float4s per slice
#define CAP 2048            // max boundary-bin candidates for the fast path

// output layout (flat float32, reference return order)
#define OFF_SCORES ((size_t)0)
#define OFF_LABELS ((size_t)1600)
#define OFF_BOXES  ((size_t)3200)
#define OFF_MASKS  ((size_t)9600)
#define OFF_SI     ((size_t)26224000)
#define OFF_LI     ((size_t)26225600)
#define OFF_LA     ((size_t)26227200)

__device__ __forceinline__ uint32_t fkey(float f) {
    uint32_t u = __float_as_uint(f);
    return (u >> 31) ? ~u : (u | 0x80000000u);
}

// wave-0 helper: given 256-bin counts, pick boundary bin for the kth largest.
// Executed by threads 0..63 (one full wave). Writes bin index, #to-take-in-bin, bin count.
__device__ __forceinline__ void pick_boundary(const uint32_t* bins, int kth, int lane,
                                              uint32_t* sBin, int* sNeed, int* sCnt) {
    uint4 h4 = *(const uint4*)&bins[lane * 4];
    uint32_t s3 = h4.w;
    uint32_t s2 = h4.z + s3;
    uint32_t s1 = h4.y + s2;
    uint32_t s0 = h4.x + s1;
    uint32_t inc = s0;
#pragma unroll
    for (int off = 1; off < 64; off <<= 1) {
        uint32_t v = __shfl_down(inc, off);
        if (lane + off < 64) inc += v;
    }
    uint32_t higher = inc - s0;   // strictly-higher lanes' total
    uint32_t sarr[4] = {s0, s1, s2, s3};
    uint32_t harr[4] = {h4.x, h4.y, h4.z, h4.w};
#pragma unroll
    for (int c = 0; c < 4; ++c) {
        int cge = (int)(sarr[c] + higher);
        int cgt = cge - (int)harr[c];
        if (cge >= kth && cgt < kth) {
            *sBin = (uint32_t)(lane * 4 + c);
            *sNeed = kth - cgt;
            *sCnt = (int)harr[c];
        }
    }
}

// ---------------- K1: pass-0 byte histogram, 8 slices/batch = 256 blocks (full chip) ------------
__global__ __launch_bounds__(256) void topk_hist(const float* __restrict__ logits,
                                                 float* __restrict__ wsD,
                                                 int* __restrict__ wsZZ,
                                                 uint32_t* __restrict__ wsH) {
    int s = blockIdx.x;   // slice 0..7
    int b = blockIdx.y;   // batch
    int t = threadIdx.x;

    // table init spread over the 8 b==0 blocks (fp64 cos, matches numpy)
    if (b == 0) {
        int lo = s * 368, hi = lo + 368;
        if (hi > 23 * 128) hi = 23 * 128;
        for (int idx = lo + t; idx < hi; idx += 256) {
            int k = idx >> 7, m = idx & 127;
            double v = cos((M_PI * (2.0 * (double)m + 1.0) * (double)k) / 256.0) * 0.125;
            if (k == 0) v *= sqrt(0.5);
            wsD[idx] = (float)v;
        }
        if (s == 0) {
            int j = t;
            int ss = 0;
            while ((ss + 1) * (ss + 2) / 2 <= j) ++ss;
            int o = j - ss * (ss + 1) / 2;
            int r = (ss & 1) ? o : (ss - o);
            int c = ss - r;
            wsZZ[j] = (r << 5) | c;
        }
    }

    __shared__ uint32_t hw[4 * 256];   // per-wave privatized (4 waves)
    for (int i = t; i < 4 * 256; i += 256) hw[i] = 0;
    __syncthreads();

    uint32_t* myh = &hw[(t >> 6) * 256];
    const float4* base4 = (const float4*)(logits + (size_t)b * QC);
    int lo4 = s * SL4;
    int hi4 = lo4 + SL4; if (hi4 > QC4) hi4 = QC4;
    for (int p4 = lo4 + t; p4 < hi4; p4 += 256) {
        float4 v = base4[p4];
        atomicAdd(&myh[fkey(v.x) >> 24], 1u);
        atomicAdd(&myh[fkey(v.y) >> 24], 1u);
        atomicAdd(&myh[fkey(v.z) >> 24], 1u);
        atomicAdd(&myh[fkey(v.w) >> 24], 1u);
    }
    __syncthreads();

    if (t < 256) {
        uint32_t sum = hw[t] + hw[256 + t] + hw[512 + t] + hw[768 + t];
        wsH[((size_t)(b * NSLICE + s)) * 256 + t] = sum;
    }
}

// ---------------- K2: boundary pick + compaction + candidate-only radix refine + emit ----------
__global__ __launch_bounds__(1024) void topk_select(const float* __restrict__ logits,
                                                    const float* __restrict__ bbox,
                                                    const float* __restrict__ actions,
                                                    const int* __restrict__ tsz,
                                                    float* __restrict__ out,
                                                    int* __restrict__ wsQ,
                                                    const uint32_t* __restrict__ wsH) {
    int b = blockIdx.x;
    int t = threadIdx.x;
    int lane = t & 63, w = t >> 6;

    __shared__ uint32_t histw[NWAVE * 256];                       // slow path (16 KB)
    __shared__ __attribute__((aligned(16))) uint32_t h2[256];     // refine hist
    __shared__ __attribute__((aligned(16))) uint32_t scn[256];
    __shared__ uint32_t sP;
    __shared__ int      sNeed, sCnt;
    __shared__ uint32_t cKey[TOPK];
    __shared__ int      cIdx[TOPK];
    __shared__ int      cntTop, cntN, cntE, sMin;
    __shared__ uint32_t candK[2][CAP];                            // 16 KB
    __shared__ int      candI[2][CAP];                            // 16 KB

    // ---- load keys (float4) ----
    const float4* base4 = (const float4*)(logits + (size_t)b * QC);
    uint32_t key[NPT4][4];
#pragma unroll
    for (int i = 0; i < NPT4; ++i) {
        int p4 = t + 1024 * i;
        if (p4 < QC4) {
            float4 v = base4[p4];
            key[i][0] = fkey(v.x); key[i][1] = fkey(v.y);
            key[i][2] = fkey(v.z); key[i][3] = fkey(v.w);
        } else {
            key[i][0] = key[i][1] = key[i][2] = key[i][3] = 0u;  // pads (guarded out below)
        }
    }

    // ---- sum the 8 slice histograms -> scn, pick pass-0 boundary bin ----
    if (t < 256) {
        uint32_t ssum = 0;
#pragma unroll
        for (int s = 0; s < NSLICE; ++s) ssum += wsH[((size_t)(b * NSLICE + s)) * 256 + t];
        scn[t] = ssum;
    }
    if (t == 0) { cntTop = 0; cntN = 0; cntE = 0; }
    __syncthreads();
    if (t < 64) pick_boundary(scn, TOPK, lane, &sP, &sNeed, &sCnt);
    __syncthreads();
    uint32_t P0 = sP << 24;     // boundary byte as full-key prefix
    int need = sNeed;           // how many to take from the boundary bin
    int nC0 = sCnt;             // boundary-bin population

    if (nC0 <= CAP) {
        // ============ FAST PATH ============
#pragma unroll
        for (int i = 0; i < NPT4; ++i) {
            int p4 = t + 1024 * i;
#pragma unroll
            for (int c = 0; c < 4; ++c) {
                if (p4 >= QC4) continue;
                uint32_t k = key[i][c];
                uint32_t hb = k & 0xFF000000u;
                if (hb > P0) {
                    int pos = atomicAdd(&cntTop, 1);
                    cKey[pos] = k; cIdx[pos] = 4 * p4 + c;
                } else if (hb == P0) {
                    int pos = atomicAdd(&cntN, 1);
                    candK[0][pos] = k; candI[0][pos] = 4 * p4 + c;
                }
            }
        }
        __syncthreads();
        int nc = cntN;          // == nC0
        int cur = 0;

        // refine with 8-bit radix levels over candidates only
        for (int level = 1; level <= 3; ++level) {
            if (nc <= need) break;       // uniform: nc >= need invariant => nc == need
            int shift = 24 - 8 * level;
            if (t < 256) h2[t] = 0;
            if (t == 0) cntN = 0;
            __syncthreads();
            for (int j2 = t; j2 < nc; j2 += 1024)
                atomicAdd(&h2[(candK[cur][j2] >> shift) & 255u], 1u);
            __syncthreads();
            if (t < 64) pick_boundary(h2, need, lane, &sP, &sNeed, &sCnt);
            __syncthreads();
            uint32_t sub = sP;
            int needN = sNeed;
            for (int j2 = t; j2 < nc; j2 += 1024) {
                uint32_t k2 = candK[cur][j2]; int i2 = candI[cur][j2];
                uint32_t sb = (k2 >> shift) & 255u;
                if (sb > sub) {
                    int pos = atomicAdd(&cntTop, 1);
                    cKey[pos] = k2; cIdx[pos] = i2;
                } else if (sb == sub) {
                    int pos = atomicAdd(&cntN, 1);
                    candK[cur ^ 1][pos] = k2; candI[cur ^ 1][pos] = i2;
                }
            }
            __syncthreads();
            nc = cntN; need = needN; cur ^= 1;
        }

        int base = cntTop;   // uniform (post-barrier, no pending atomics)
        if (nc <= need) {
            for (int j2 = t; j2 < nc; j2 += 1024) {
                cKey[base + j2] = candK[cur][j2];
                cIdx[base + j2] = candI[cur][j2];
            }
        } else {
            for (int j2 = t; j2 < nc; j2 += 1024) {
                int my = candI[cur][j2];
                int rank = 0;
                for (int m = 0; m < nc; ++m) rank += (candI[cur][m] < my);
                if (rank < need) { cKey[base + rank] = candK[cur][j2]; cIdx[base + rank] = my; }
            }
        }
        __syncthreads();
    } else {
        // ============ SLOW FALLBACK (4-pass radix + proven tie handling) ============
        uint32_t Pfull = P0;
        int kth = need;
        uint32_t* myh = &histw[w * 256];
        for (int pass = 1; pass < 4; ++pass) {
            int shift = 24 - 8 * pass;
            for (int i2 = t; i2 < NWAVE * 256; i2 += 1024) histw[i2] = 0;
            __syncthreads();
            uint32_t pmask = 0xFFFFFFFFu << (shift + 8);
#pragma unroll
            for (int i2 = 0; i2 < NPT4; ++i2)
#pragma unroll
                for (int c = 0; c < 4; ++c) {
                    uint32_t k2 = key[i2][c];
                    if ((k2 & pmask) == Pfull) atomicAdd(&myh[(k2 >> shift) & 255u], 1u);
                }
            __syncthreads();
            if (t < 256) {
                uint32_t ssum = 0;
#pragma unroll
                for (int ww = 0; ww < NWAVE; ++ww) ssum += histw[ww * 256 + t];
                scn[t] = ssum;
            }
            __syncthreads();
            if (t < 64) pick_boundary(scn, kth, lane, &sP, &sNeed, &sCnt);
            __syncthreads();
            Pfull |= (sP << shift);
            kth = sNeed;
        }
        if (t == 0) { cntTop = 0; cntE = 0; }
        __syncthreads();
#pragma unroll
        for (int i2 = 0; i2 < NPT4; ++i2) {
            int p4 = t + 1024 * i2;
#pragma unroll
            for (int c = 0; c < 4; ++c) {
                if (p4 >= QC4) continue;
                uint32_t k2 = key[i2][c];
                if (k2 > Pfull) {
                    int pos = atomicAdd(&cntTop, 1);
                    cKey[pos] = k2; cIdx[pos] = 4 * p4 + c;
                } else if (k2 == Pfull) {
                    int pos = atomicAdd(&cntE, 1);
                    if (pos < CAP) candI[0][pos] = 4 * p4 + c;
                }
            }
        }
        __syncthreads();
        int cgt2 = cntTop;   // == TOPK - kth
        int ne = cntE;
        if (ne <= CAP) {
            for (int j2 = t; j2 < ne; j2 += 1024) {
                int my = candI[0][j2];
                int rank = 0;
                for (int m = 0; m < ne; ++m) rank += (candI[0][m] < my);
                if (rank < kth) { cKey[cgt2 + rank] = Pfull; cIdx[cgt2 + rank] = my; }
            }
            __syncthreads();
        } else {
            for (int r = 0; r < kth; ++r) {
                if (t == 0) sMin = 0x7fffffff;
                __syncthreads();
                int loc = 0x7fffffff;
#pragma unroll
                for (int i2 = 0; i2 < NPT4; ++i2) {
                    int p4 = t + 1024 * i2;
#pragma unroll
                    for (int c = 0; c < 4; ++c)
                        if (p4 < QC4 && key[i2][c] == Pfull) loc = min(loc, 4 * p4 + c);
                }
                atomicMin(&sMin, loc);
                __syncthreads();
                int m = sMin;
#pragma unroll
                for (int i2 = 0; i2 < NPT4; ++i2) {
                    int p4 = t + 1024 * i2;
#pragma unroll
                    for (int c = 0; c < 4; ++c)
                        if (4 * p4 + c == m) key[i2][c] = 0;
                }
                if (t == 0) { cKey[cgt2 + r] = Pfull; cIdx[cgt2 + r] = m; }
                __syncthreads();
            }
        }
    }

    // ---- rank 50 winners (key desc, index asc) and emit ----
    if (t < TOPK) {
        uint32_t myk = cKey[t]; int myi = cIdx[t];
        int rank = 0;
        for (int m = 0; m < TOPK; ++m) {
            uint32_t ok = cKey[m]; int oi = cIdx[m];
            rank += (ok > myk) || (ok == myk && oi < myi);
        }
        uint32_t u = (myk >> 31) ? (myk & 0x7fffffffu) : ~myk;
        float val = __uint_as_float(u);
        int q = myi / CC;
        int label = myi - q * CC;
        out[OFF_SCORES + b * TOPK + rank] = 1.0f / (1.0f + expf(-val));
        out[OFF_LABELS + b * TOPK + rank] = (float)label;
        wsQ[b * TOPK + rank] = q;
        const float* bbp = bbox + ((size_t)(b * QQ + q)) * 4;
        float cx = bbp[0], cy = bbp[1], bw = bbp[2], bh = bbp[3];
        float ih = (float)tsz[b * 2 + 0];
        float iw = (float)tsz[b * 2 + 1];
        float* bo = out + OFF_BOXES + ((size_t)(b * TOPK + rank)) * 4;
        bo[0] = (cx - 0.5f * bw) * iw;
        bo[1] = (cy - 0.5f * bh) * ih;
        bo[2] = (cx + 0.5f * bw) * iw;
        bo[3] = (cy + 0.5f * bh) * ih;
    }
    if (t == 0) {
        const float* ap = actions + (size_t)b * 10;
        float bv = ap[0]; int bi = 0;
        for (int i = 1; i < 10; ++i) { if (ap[i] > bv) { bv = ap[i]; bi = i; } }
        out[OFF_LA + b] = (float)bi;
    }
}

// ---------------- per-(b,rank) mask DCT + threshold + interms ----------------
// LDS-issue-reduced: D read from global (L1-resident, vmem pipe) in BOTH stages;
// stage 1 exploits B's anti-triangular support (k+l <= 22) with compile-time l.
// LDS = sT (11.8K) + sB (2.2K) only.
__global__ __launch_bounds__(256) void mask_kernel(const float* __restrict__ vec,
                                                   const float* __restrict__ interms,
                                                   const int* __restrict__ wsQ,
                                                   const float* __restrict__ wsD,
                                                   const int* __restrict__ wsZZ,
                                                   float* __restrict__ out) {
    int j = blockIdx.x;      // rank 0..49
    int b = blockIdx.y;      // batch
    int t = threadIdx.x;

    __shared__ float sT[23 * 128];
    __shared__ float sB[23 * 24];
    __shared__ float redv[4];
    __shared__ int   redi[4];
    __shared__ float redmn[4], redmx[4];

    int q = wsQ[b * TOPK + j];

    for (int i = t; i < 23 * 24; i += 256) sB[i] = 0.0f;
    __syncthreads();

    // scatter the 256 kept coefficients into zigzag positions (k+l <= 22)
    {
        int kl = wsZZ[t];
        float x = vec[((size_t)(b * QQ + q)) * NKEEP + t];
        sB[(kl >> 5) * 24 + (kl & 31)] = x;
    }

    // interms argmax/max over 91 classes (sigmoid is monotone)
    int lane = t & 63, w = t >> 6;
    {
        float x = (t < CC) ? interms[((size_t)(b * QQ + q)) * CC + t] : -INFINITY;
        int xi = (t < CC) ? t : 0x7fffffff;
#pragma unroll
        for (int off = 32; off >= 1; off >>= 1) {
            float ov = __shfl_down(x, off);
            int   oi = __shfl_down(xi, off);
            bool better = (ov > x) || (ov == x && oi < xi);
            x = better ? ov : x;
            xi = better ? oi : xi;
        }
        if (lane == 0) { redv[w] = x; redi[w] = xi; }
    }
    __syncthreads();   // guards sB scatter + redv/redi

    if (t == 0) {
        float gv = redv[0]; int gi = redi[0];
        for (int k = 1; k < 4; ++k) {
            bool better = (redv[k] > gv) || (redv[k] == gv && redi[k] < gi);
            gv = better ? redv[k] : gv;
            gi = better ? redi[k] : gi;
        }
        out[OFF_SI + (size_t)b * TOPK + j] = 1.0f / (1.0f + expf(-gv));
        out[OFF_LI + (size_t)b * TOPK + j] = (float)gi;
    }

    // stage 1: T[l][n] = sum_{k <= 22-l} D[k][n] * B[k][l]
    // l is wave-uniform (h = t>>7 selects even/odd l), compile-time via macro -> the
    // triangular k-bound is static: ~138 sB broadcast reads/thread instead of 276.
    // D[k][n] comes from GLOBAL wsD (coalesced, L1-resident) -> zero LDS issue for D.
    {
        int n = t & 127, h = t >> 7;
        float Dn[23];
#pragma unroll
        for (int k = 0; k < 23; ++k) Dn[k] = wsD[k * 128 + n];
#define S1L(L) { float a1 = 0.0f; \
    _Pragma("unroll") \
    for (int k = 0; k <= 22 - (L); ++k) a1 += Dn[k] * sB[k * 24 + (L)]; \
    sT[(L) * 128 + n] = a1; }
        if (h == 0) {
            S1L(0) S1L(2) S1L(4) S1L(6) S1L(8) S1L(10)
            S1L(12) S1L(14) S1L(16) S1L(18) S1L(20) S1L(22)
        } else {
            S1L(1) S1L(3) S1L(5) S1L(7) S1L(9) S1L(11)
            S1L(13) S1L(15) S1L(17) S1L(19) S1L(21)
        }
#undef S1L
    }
    __syncthreads();

    // stage 2: out[n][m] = sum_l T[l][n] * D[l][m]
    // T from LDS (broadcast reads); D from GLOBAL (L1) -> no 4-way LDS bank conflict,
    // D traffic moves to the vmem pipe and overlaps the LDS reads.
    int tr = t >> 4, tc = t & 15;
    float acc[8][8];
#pragma unroll
    for (int a = 0; a < 8; ++a)
#pragma unroll
        for (int c = 0; c < 8; ++c) acc[a][c] = 0.0f;

#pragma unroll 4
    for (int l = 0; l < 23; ++l) {
        const float4 Ta = *(const float4*)&sT[l * 128 + tr * 8];
        const float4 Tb = *(const float4*)&sT[l * 128 + tr * 8 + 4];
        const float4 Da = *(const float4*)&wsD[l * 128 + tc * 8];
        const float4 Db = *(const float4*)&wsD[l * 128 + tc * 8 + 4];
        float Tv[8] = {Ta.x, Ta.y, Ta.z, Ta.w, Tb.x, Tb.y, Tb.z, Tb.w};
        float Dv[8] = {Da.x, Da.y, Da.z, Da.w, Db.x, Db.y, Db.z, Db.w};
#pragma unroll
        for (int a = 0; a < 8; ++a)
#pragma unroll
            for (int c = 0; c < 8; ++c) acc[a][c] += Tv[a] * Dv[c];
    }

    // block min/max
    float mn = acc[0][0], mx = acc[0][0];
#pragma unroll
    for (int a = 0; a < 8; ++a)
#pragma unroll
        for (int c = 0; c < 8; ++c) {
            mn = fminf(mn, acc[a][c]);
            mx = fmaxf(mx, acc[a][c]);
        }
#pragma unroll
    for (int off = 32; off >= 1; off >>= 1) {
        mn = fminf(mn, __shfl_down(mn, off));
        mx = fmaxf(mx, __shfl_down(mx, off));
    }
    if (lane == 0) { redmn[w] = mn; redmx[w] = mx; }
    __syncthreads();
    float gmn = fminf(fminf(redmn[0], redmn[1]), fminf(redmn[2], redmn[3]));
    float gmx = fmaxf(fmaxf(redmx[0], redmx[1]), fmaxf(redmx[2], redmx[3]));
    float thr = 0.5f * (gmx + gmn);

    size_t bse = OFF_MASKS + ((size_t)(b * TOPK + j)) * 16384 + (size_t)tc * 8;
#pragma unroll
    for (int a = 0; a < 8; ++a) {
        int n = tr * 8 + a;
        float4 w0 = make_float4(acc[a][0] > thr ? 1.0f : 0.0f,
                                acc[a][1] > thr ? 1.0f : 0.0f,
                                acc[a][2] > thr ? 1.0f : 0.0f,
                                acc[a][3] > thr ? 1.0f : 0.0f);
        float4 w1 = make_float4(acc[a][4] > thr ? 1.0f : 0.0f,
                                acc[a][5] > thr ? 1.0f : 0.0f,
                                acc[a][6] > thr ? 1.0f : 0.0f,
                                acc[a][7] > thr ? 1.0f : 0.0f);
        *(float4*)&out[bse + (size_t)n * 128]     = w0;
        *(float4*)&out[bse + (size_t)n * 128 + 4] = w1;
    }
}

extern "C" void kernel_launch(void* const* d_in, const int* in_sizes, int n_in,
                              void* d_out, int out_size, void* d_ws, size_t ws_size,
                              hipStream_t stream) {
    const float* logits  = (const float*)d_in[0];
    const float* bbox    = (const float*)d_in[1];
    const float* vec     = (const float*)d_in[2];
    const float* interms = (const float*)d_in[3];
    const float* actions = (const float*)d_in[4];
    const int*   tsz     = (const int*)d_in[5];
    float* out = (float*)d_out;

    float*    wsD  = (float*)d_ws;             // 23*128 = 2944 floats
    int*      wsZZ = (int*)(wsD + 2944);       // 256 ints
    int*      wsQ  = wsZZ + 256;               // 1600 ints
    uint32_t* wsH  = (uint32_t*)(wsQ + 1600);  // 32*8*256 = 65536 u32 (256 KB)

    hipLaunchKernelGGL(topk_hist, dim3(NSLICE, BB), dim3(256), 0, stream,
                       logits, wsD, wsZZ, wsH);
    hipLaunchKernelGGL(topk_select, dim3(BB), dim3(1024), 0, stream,
                       logits, bbox, actions, tsz, out, wsQ, wsH);
    hipLaunchKernelGGL(mask_kernel, dim3(TOPK, BB), dim3(256), 0, stream,
                       vec, interms, wsQ, wsD, wsZZ, out);
}